// Round 9
// baseline (200.984 us; speedup 1.0000x reference)
//
#include <hip/hip_runtime.h>

typedef __bf16 bf16;
typedef __bf16 bf16x8 __attribute__((ext_vector_type(8)));
typedef __bf16 bf16x4 __attribute__((ext_vector_type(4)));
typedef float  f32x2  __attribute__((ext_vector_type(2)));
typedef float  f32x4  __attribute__((ext_vector_type(4)));
typedef float  f32x8  __attribute__((ext_vector_type(8)));
typedef float  f32x16 __attribute__((ext_vector_type(16)));
typedef unsigned int u32x4 __attribute__((ext_vector_type(4)));

#define MFMA16(a, b, c) __builtin_amdgcn_mfma_f32_16x16x32_bf16((a), (b), (c), 0, 0, 0)
#define MFMA32(a, b, c) __builtin_amdgcn_mfma_f32_32x32x16_bf16((a), (b), (c), 0, 0, 0)

// async global->LDS, 16B per lane, LDS dst = wave-uniform base + lane*16
__device__ __forceinline__ void gload_lds16(const bf16* g, bf16* l) {
  __builtin_amdgcn_global_load_lds(
      (const __attribute__((address_space(1))) void*)g,
      (__attribute__((address_space(3))) void*)l, 16, 0, 0);
}

// ---------------- prep kernels ----------------

__global__ __launch_bounds__(256) void cast_bf16_kernel(
    const float* __restrict__ in, bf16* __restrict__ out, int n4) {
  int i = blockIdx.x * 256 + threadIdx.x;
  if (i < n4) {
    float4 v = reinterpret_cast<const float4*>(in)[i];
    bf16x4 o;
    o[0] = (bf16)v.x; o[1] = (bf16)v.y; o[2] = (bf16)v.z; o[3] = (bf16)v.w;
    reinterpret_cast<bf16x4*>(out)[i] = o;
  }
}

__global__ __launch_bounds__(256) void transpose_cast_kernel(
    const float* __restrict__ W, bf16* __restrict__ Wt, int K, int N) {
  __shared__ bf16 tile[64 * 66];
  const int k0 = blockIdx.y * 64, n0 = blockIdx.x * 64;
  const int c = threadIdx.x & 63, rb = threadIdx.x >> 6;
#pragma unroll
  for (int p = 0; p < 16; ++p) {
    int r = p * 4 + rb;
    tile[c * 66 + r] = (bf16)W[(long)(k0 + r) * N + n0 + c];
  }
  __syncthreads();
#pragma unroll
  for (int p = 0; p < 16; ++p) {
    int r = p * 4 + rb;
    Wt[(long)(n0 + r) * K + k0 + c] = tile[r * 66 + c];
  }
}

// ---------------- GEMM: C(M,N) = A(M,K) @ Bt(N,K)^T, m97 structure ----------------
template <int EPI>
__global__ __launch_bounds__(256, 2) void gemm_bt(
    const bf16* __restrict__ A, const bf16* __restrict__ Bt,
    const float* __restrict__ bias, bf16* __restrict__ oQ,
    bf16* __restrict__ oK, bf16* __restrict__ oVT, float* __restrict__ oC,
    int K) {
  __shared__ bf16 As[128 * 64];
  __shared__ bf16 Bs[128 * 64];
  const int tid = threadIdx.x, lane = tid & 63, wid = tid >> 6;
  const int wr = wid >> 1, wc = wid & 1;
  const int brow = blockIdx.x * 128, bcol = blockIdx.y * 128;
  const int srow = lane >> 3, scol8 = (lane & 7) * 8;
  const int c15 = lane & 15, g = lane >> 4;

  f32x4 acc[4][4];
#pragma unroll
  for (int m = 0; m < 4; ++m)
#pragma unroll
    for (int n = 0; n < 4; ++n) acc[m][n] = f32x4{0.f, 0.f, 0.f, 0.f};

  const bf16* Ab = A + (long)brow * K + scol8;
  const bf16* Bb = Bt + (long)bcol * K + scol8;

  for (int k0 = 0; k0 < K; k0 += 64) {
#pragma unroll
    for (int i = 0; i < 4; ++i) {
      int c = wid * 4 + i;
      int row = c * 8 + srow;
      gload_lds16(Ab + (long)row * K + k0, &As[c * 512]);
    }
#pragma unroll
    for (int i = 0; i < 4; ++i) {
      int c = wid * 4 + i;
      int row = c * 8 + srow;
      gload_lds16(Bb + (long)row * K + k0, &Bs[c * 512]);
    }
    __syncthreads();
#pragma unroll
    for (int kk = 0; kk < 64; kk += 32) {
      bf16x8 a[4], b[4];
#pragma unroll
      for (int m = 0; m < 4; ++m)
        a[m] = *(const bf16x8*)&As[(wr * 64 + m * 16 + c15) * 64 + kk + g * 8];
#pragma unroll
      for (int n = 0; n < 4; ++n)
        b[n] = *(const bf16x8*)&Bs[(wc * 64 + n * 16 + c15) * 64 + kk + g * 8];
#pragma unroll
      for (int m = 0; m < 4; ++m)
#pragma unroll
        for (int n = 0; n < 4; ++n)
          acc[m][n] = MFMA16(a[m], b[n], acc[m][n]);
    }
    __syncthreads();
  }

#pragma unroll
  for (int n = 0; n < 4; ++n) {
    const int col = bcol + wc * 64 + n * 16 + c15;
    const float bv = bias[col];
    if (EPI == 0) {
      const int which = col >> 10, wi = col & 1023, h = wi >> 6, d = wi & 63;
      const float sc = (which == 0) ? 0.18033688011112042f : 1.0f;  // 0.125*log2(e)
#pragma unroll
      for (int m = 0; m < 4; ++m) {
        const int row0 = brow + wr * 64 + m * 16 + g * 4;
        const int bb = row0 >> 11, t0 = row0 & 2047;
        const long hb = bb * 16 + h;
        if (which == 2) {
          bf16x4 pv;
#pragma unroll
          for (int r = 0; r < 4; ++r) pv[r] = (bf16)(acc[m][n][r] + bv);
          *(bf16x4*)&oVT[(hb * 64 + d) * 2048 + t0] = pv;  // (b,h,d,t)
        } else {
          bf16* dst = ((which == 0) ? oQ : oK) + (hb * 2048 + t0) * 64 + d;
#pragma unroll
          for (int r = 0; r < 4; ++r)
            dst[(long)r * 64] = (bf16)((acc[m][n][r] + bv) * sc);
        }
      }
    } else {
#pragma unroll
      for (int m = 0; m < 4; ++m) {
        const long row = brow + wr * 64 + m * 16 + g * 4;
#pragma unroll
        for (int r = 0; r < 4; ++r) oC[(row + r) * 1024 + col] = acc[m][n][r] + bv;
      }
    }
  }
}

// ---------------- flash attention: LDS-staged K/V, split x2, overlapped body -
// 1024 blocks (32 bh x 16 q-blocks x 2 splits) x 4 waves sharing staged 64-key
// K/V tiles. Round-9 change: BOTH subtiles' QK^T issued upfront (8 MFMA) so
// softmax(A) VALU overlaps stB's MFMA and PV(A) overlaps softmax(B); subtile
// order rotated by wave parity to de-phase the 4 waves' VALU bursts.
__global__ __launch_bounds__(256, 4) void attn_kernel(
    const bf16* __restrict__ Q, const bf16* __restrict__ K,
    const bf16* __restrict__ VT, const int* __restrict__ mask,
    float* __restrict__ O_part, float* __restrict__ ml_part) {
  __shared__ bf16 Kl[2][4096];  // [buf][64 keys x 64 kdim], 8-elem groups XOR-swizzled
  __shared__ bf16 Vl[2][4096];  // [buf][64 d x 64 keys], same swizzle
  __shared__ float sws[4][32];  // rare-path rescale broadcast
  const int tid = threadIdx.x, lane = tid & 63, w = tid >> 6;
  const int col = lane & 31, hi = lane >> 5, c7 = col & 7;
  const int bid = blockIdx.x;
  const int swz = (bid & 7) * 128 + (bid >> 3);  // XCD swizzle: 4 bh per XCD
  const int bh = swz >> 5, rem = swz & 31;
  const int s = rem & 1, qb = rem >> 1;
  const int b = bh >> 4, h = bh & 15;
  const int q0 = qb * 128 + w * 32;
  const int koff0 = s * 1024;

  const bf16* Kbase = K + (long)bh * 2048 * 64;
  const bf16* Vbase = VT + (long)bh * 64 * 2048;
  const int* mb = mask + b * 2048;

  const int srow = lane >> 3;
  const int xoff = ((lane & 7) ^ srow) << 3;

  auto stage = [&](int buf, int t) {
    const int koff = koff0 + t * 64;
#pragma unroll
    for (int i = 0; i < 2; ++i) {
      const int c = w * 2 + i;
      gload_lds16(Kbase + (long)(koff + c * 8 + srow) * 64 + xoff,
                  &Kl[buf][c * 512]);
      gload_lds16(Vbase + (long)(c * 8 + srow) * 2048 + koff + xoff,
                  &Vl[buf][c * 512]);
    }
  };

  // Q B-frag (pre-scaled by 0.125*log2e in gemm epilogue)
  const bf16* Qp = Q + ((long)bh * 2048 + q0 + col) * 64 + hi * 8;
  bf16x8 bq[4];
#pragma unroll
  for (int dc = 0; dc < 4; ++dc) bq[dc] = *(const bf16x8*)(Qp + dc * 16);

  f32x16 o0, o1;
#pragma unroll
  for (int r = 0; r < 16; ++r) { o0[r] = 0.f; o1[r] = 0.f; }
  float mrun = -1e30f, lrun = 0.f;  // lrun = per-half partial until fold

  // softmax + pack for one 32-key subtile (st in place -> P A-frags)
  auto process = [&](f32x16& st, int mv, bf16x8& pa0, bf16x8& pa1) {
    unsigned km32 = (unsigned)__ballot(mv != 0);
    if (km32 != 0xffffffffu) {
      unsigned km = km32 >> (hi * 4);
#pragma unroll
      for (int r = 0; r < 16; ++r)
        if (!((km >> ((r & 3) + 8 * (r >> 2))) & 1)) st[r] = -1e30f;
    }
    // per-half row max (tree; clang fuses to max3 where useful)
    float m01 = fmaxf(st[0], st[1]), m23 = fmaxf(st[2], st[3]);
    float m45 = fmaxf(st[4], st[5]), m67 = fmaxf(st[6], st[7]);
    float m89 = fmaxf(st[8], st[9]), mab = fmaxf(st[10], st[11]);
    float mcd = fmaxf(st[12], st[13]), mef = fmaxf(st[14], st[15]);
    float m0 = fmaxf(fmaxf(fmaxf(m01, m23), fmaxf(m45, m67)),
                     fmaxf(fmaxf(m89, mab), fmaxf(mcd, mef)));
    if (__any(m0 > mrun + 8.0f)) {  // defer-max rescale (rare)
      float pm = fmaxf(m0, __shfl_xor(m0, 32));
      float mnew = fmaxf(mrun, pm);
      float scale = __builtin_exp2f(mrun - mnew);
      mrun = mnew;
      lrun *= scale;
      if (hi == 0) sws[w][col] = scale;
      asm volatile("s_waitcnt lgkmcnt(0)" ::: "memory");
#pragma unroll
      for (int r = 0; r < 16; ++r) {
        float sc = sws[w][(r & 3) + 8 * (r >> 2) + 4 * hi];
        o0[r] *= sc; o1[r] *= sc;
      }
    }
#pragma unroll
    for (int r = 0; r < 16; ++r) st[r] = __builtin_exp2f(st[r] - mrun);
    // row-sum: vector adds (packed-f32 friendly)
    f32x8 lo8 = __builtin_shufflevector(st, st, 0, 1, 2, 3, 4, 5, 6, 7);
    f32x8 hi8 = __builtin_shufflevector(st, st, 8, 9, 10, 11, 12, 13, 14, 15);
    f32x8 s8 = lo8 + hi8;
    f32x4 s4 = __builtin_shufflevector(s8, s8, 0, 1, 2, 3) +
               __builtin_shufflevector(s8, s8, 4, 5, 6, 7);
    f32x2 s2 = __builtin_shufflevector(s4, s4, 0, 1) +
               __builtin_shufflevector(s4, s4, 2, 3);
    lrun += s2[0] + s2[1];
    // P -> bf16 A-frags; 4 cross-half exchanges in one window
    unsigned d0, d1, d2, d3, d4, d5, d6, d7;
    {
      union { bf16 hh[2]; unsigned u; } tt;
      tt.hh[0] = (bf16)st[0];  tt.hh[1] = (bf16)st[1];  d0 = tt.u;
      tt.hh[0] = (bf16)st[2];  tt.hh[1] = (bf16)st[3];  d1 = tt.u;
      tt.hh[0] = (bf16)st[4];  tt.hh[1] = (bf16)st[5];  d2 = tt.u;
      tt.hh[0] = (bf16)st[6];  tt.hh[1] = (bf16)st[7];  d3 = tt.u;
      tt.hh[0] = (bf16)st[8];  tt.hh[1] = (bf16)st[9];  d4 = tt.u;
      tt.hh[0] = (bf16)st[10]; tt.hh[1] = (bf16)st[11]; d5 = tt.u;
      tt.hh[0] = (bf16)st[12]; tt.hh[1] = (bf16)st[13]; d6 = tt.u;
      tt.hh[0] = (bf16)st[14]; tt.hh[1] = (bf16)st[15]; d7 = tt.u;
    }
    unsigned g02 = (unsigned)__shfl_xor((int)(hi ? d0 : d2), 32);
    unsigned g13 = (unsigned)__shfl_xor((int)(hi ? d1 : d3), 32);
    unsigned g46 = (unsigned)__shfl_xor((int)(hi ? d4 : d6), 32);
    unsigned g57 = (unsigned)__shfl_xor((int)(hi ? d5 : d7), 32);
    u32x4 w0 = {hi ? g02 : d0, hi ? g13 : d1, hi ? d2 : g02, hi ? d3 : g13};
    u32x4 w1 = {hi ? g46 : d4, hi ? g57 : d5, hi ? d6 : g46, hi ? d7 : g57};
    pa0 = __builtin_bit_cast(bf16x8, w0);
    pa1 = __builtin_bit_cast(bf16x8, w1);
  };

  stage(0, 0);
  for (int t = 0; t < 16; ++t) {
    const int cur = t & 1;
    __builtin_amdgcn_s_barrier();  // prev tile's LDS reads done before overwrite
    if (t < 15) {
      stage(cur ^ 1, t + 1);
      asm volatile("s_waitcnt vmcnt(4)" ::: "memory");  // tile t staged; t+1 in flight
    } else {
      asm volatile("s_waitcnt vmcnt(0)" ::: "memory");
    }
    __builtin_amdgcn_s_barrier();  // all waves' chunks of tile t visible

    // wave-parity rotation: de-phase the 4 waves' VALU bursts
    const int sA = w & 1, sB = sA ^ 1;
    // mask values in flight early
    const int mvA = mb[koff0 + t * 64 + sA * 32 + col];
    const int mvB = mb[koff0 + t * 64 + sB * 32 + col];
    // K A-frags for BOTH subtiles
    const bf16* KrA = &Kl[cur][(sA * 32 + col) * 64];
    const bf16* KrB = &Kl[cur][(sB * 32 + col) * 64];
    bf16x8 akA0 = *(const bf16x8*)(KrA + (((0 + hi) ^ c7) << 3));
    bf16x8 akA1 = *(const bf16x8*)(KrA + (((2 + hi) ^ c7) << 3));
    bf16x8 akA2 = *(const bf16x8*)(KrA + (((4 + hi) ^ c7) << 3));
    bf16x8 akA3 = *(const bf16x8*)(KrA + (((6 + hi) ^ c7) << 3));
    bf16x8 akB0 = *(const bf16x8*)(KrB + (((0 + hi) ^ c7) << 3));
    bf16x8 akB1 = *(const bf16x8*)(KrB + (((2 + hi) ^ c7) << 3));
    bf16x8 akB2 = *(const bf16x8*)(KrB + (((4 + hi) ^ c7) << 3));
    bf16x8 akB3 = *(const bf16x8*)(KrB + (((6 + hi) ^ c7) << 3));
    // QK^T for both subtiles issued upfront (MFMA fills while softmax runs)
    f32x16 stA, stB;
#pragma unroll
    for (int r = 0; r < 16; ++r) { stA[r] = 0.f; stB[r] = 0.f; }
    __builtin_amdgcn_s_setprio(1);
    stA = MFMA32(akA0, bq[0], stA);
    stA = MFMA32(akA1, bq[1], stA);
    stA = MFMA32(akA2, bq[2], stA);
    stA = MFMA32(akA3, bq[3], stA);
    stB = MFMA32(akB0, bq[0], stB);
    stB = MFMA32(akB1, bq[1], stB);
    stB = MFMA32(akB2, bq[2], stB);
    stB = MFMA32(akB3, bq[3], stB);
    __builtin_amdgcn_s_setprio(0);

    const bf16* Vrow0 = &Vl[cur][col * 64];
    const bf16* Vrow1 = &Vl[cur][(col + 32) * 64];

    // ---- subtile A: softmax (overlaps stB MFMA) then PV ----
    bf16x8 paA0, paA1;
    process(stA, mvA, paA0, paA1);
    {
      const int g0 = ((sA * 4 + hi) ^ c7) << 3;
      const int g1 = ((sA * 4 + 2 + hi) ^ c7) << 3;
      bf16x8 bv00 = *(const bf16x8*)(Vrow0 + g0);
      bf16x8 bv10 = *(const bf16x8*)(Vrow0 + g1);
      bf16x8 bv01 = *(const bf16x8*)(Vrow1 + g0);
      bf16x8 bv11 = *(const bf16x8*)(Vrow1 + g1);
      __builtin_amdgcn_s_setprio(1);
      o0 = MFMA32(paA0, bv00, o0);
      o0 = MFMA32(paA1, bv10, o0);
      o1 = MFMA32(paA0, bv01, o1);
      o1 = MFMA32(paA1, bv11, o1);
      __builtin_amdgcn_s_setprio(0);
    }
    // ---- subtile B: softmax (overlaps PV(A) MFMA) then PV ----
    bf16x8 paB0, paB1;
    process(stB, mvB, paB0, paB1);
    {
      const int g0 = ((sB * 4 + hi) ^ c7) << 3;
      const int g1 = ((sB * 4 + 2 + hi) ^ c7) << 3;
      bf16x8 bv00 = *(const bf16x8*)(Vrow0 + g0);
      bf16x8 bv10 = *(const bf16x8*)(Vrow0 + g1);
      bf16x8 bv01 = *(const bf16x8*)(Vrow1 + g0);
      bf16x8 bv11 = *(const bf16x8*)(Vrow1 + g1);
      __builtin_amdgcn_s_setprio(1);
      o0 = MFMA32(paB0, bv00, o0);
      o0 = MFMA32(paB1, bv10, o0);
      o1 = MFMA32(paB0, bv01, o1);
      o1 = MFMA32(paB1, bv11, o1);
      __builtin_amdgcn_s_setprio(0);
    }
  }

  // ---- write raw partial (O, m, l) for cross-block merge ----
  lrun += __shfl_xor(lrun, 32);  // fold per-half l partials
  if (hi == 0) {
    float2 v; v.x = mrun; v.y = lrun;
    *(float2*)&ml_part[((long)s * 65536 + bh * 2048 + q0 + col) * 2] = v;
  }
  float* Os = O_part + (long)s * 4194304;
#pragma unroll
  for (int r = 0; r < 16; ++r) {
    const int qr = (r & 3) + 8 * (r >> 2) + 4 * hi;
    long base = ((long)b * 2048 + q0 + qr) * 1024 + h * 64 + col;
    Os[base] = o0[r];
    Os[base + 32] = o1[r];
  }
}

// ---------------- merge the 2 KV-split partials -> Aatt (bf16) ---------------
__global__ __launch_bounds__(256) void attn_merge_kernel(
    const float* __restrict__ O_part, const float* __restrict__ ml_part,
    bf16* __restrict__ Aout) {
  const int i = blockIdx.x * 256 + threadIdx.x;  // float4 group over 4096x1024
  const int qg = i >> 8;                         // global query row
  const int h = (i & 255) >> 4;
  const int bq = qg >> 11, t = qg & 2047;
  const int bh = bq * 16 + h;
  const float2 ml0 = *(const float2*)&ml_part[((long)bh * 2048 + t) * 2];
  const float2 ml1 = *(const float2*)&ml_part[((long)65536 + bh * 2048 + t) * 2];
  const float ms = fmaxf(ml0.x, ml1.x);
  const float w0 = __builtin_exp2f(ml0.x - ms);
  const float w1 = __builtin_exp2f(ml1.x - ms);
  const float inv = 1.0f / (w0 * ml0.y + w1 * ml1.y);
  float4 a = ((const float4*)O_part)[i];
  float4 c = ((const float4*)(O_part + 4194304))[i];
  bf16x4 o;
  o[0] = (bf16)((w0 * a.x + w1 * c.x) * inv);
  o[1] = (bf16)((w0 * a.y + w1 * c.y) * inv);
  o[2] = (bf16)((w0 * a.z + w1 * c.z) * inv);
  o[3] = (bf16)((w0 * a.w + w1 * c.w) * inv);
  ((bf16x4*)Aout)[i] = o;
}

// ---------------- launcher ----------------
extern "C" void kernel_launch(void* const* d_in, const int* in_sizes, int n_in,
                              void* d_out, int out_size, void* d_ws,
                              size_t ws_size, hipStream_t stream) {
  const float* x    = (const float*)d_in[0];
  const int*   mask = (const int*)d_in[1];
  const float* Wqkv = (const float*)d_in[2];
  const float* bqkv = (const float*)d_in[3];
  const float* Wout = (const float*)d_in[4];
  const float* bout = (const float*)d_in[5];
  float* out = (float*)d_out;

  char* ws = (char*)d_ws;
  bf16* xb    = (bf16*)(ws);                      // 8 MB; reused as Aatt
  bf16* wqkvT = (bf16*)(ws + (8u << 20));         // 6 MB
  bf16* woutT = (bf16*)(ws + (14u << 20));        // 2 MB
  bf16* Qb    = (bf16*)(ws + (16u << 20));        // 8 MB (b,h,t,d)
  bf16* Kb    = (bf16*)(ws + (24u << 20));        // 8 MB (b,h,t,d)
  bf16* VTb   = (bf16*)(ws + (32u << 20));        // 8 MB (b,h,d,t)
  float* Opart = (float*)(ws + (40u << 20));      // 32 MB (2 splits, fp32)
  float* mlp   = (float*)(ws + (72u << 20));      // 1 MB
  bf16* Aatt  = xb;

  cast_bf16_kernel<<<4096, 256, 0, stream>>>(x, xb, (4096 * 1024) / 4);
  transpose_cast_kernel<<<dim3(48, 16), 256, 0, stream>>>(Wqkv, wqkvT, 1024, 3072);
  transpose_cast_kernel<<<dim3(16, 16), 256, 0, stream>>>(Wout, woutT, 1024, 1024);
  gemm_bt<0><<<dim3(32, 24), 256, 0, stream>>>(xb, wqkvT, bqkv, Qb, Kb, VTb,
                                               nullptr, 1024);
  attn_kernel<<<1024, 256, 0, stream>>>(Qb, Kb, VTb, mask, Opart, mlp);
  attn_merge_kernel<<<4096, 256, 0, stream>>>(Opart, mlp, Aatt);
  gemm_bt<1><<<dim3(32, 8), 256, 0, stream>>>(Aatt, woutT, bout, nullptr,
                                              nullptr, nullptr, out, 1024);
}

// Round 10
// 174.040 us; speedup vs baseline: 1.1548x; 1.1548x over previous
//
#include <hip/hip_runtime.h>

typedef __bf16 bf16;
typedef __bf16 bf16x8 __attribute__((ext_vector_type(8)));
typedef __bf16 bf16x4 __attribute__((ext_vector_type(4)));
typedef float  f32x4  __attribute__((ext_vector_type(4)));
typedef float  f32x16 __attribute__((ext_vector_type(16)));
typedef unsigned int u32x4 __attribute__((ext_vector_type(4)));

#define MFMA16(a, b, c) __builtin_amdgcn_mfma_f32_16x16x32_bf16((a), (b), (c), 0, 0, 0)
#define MFMA32(a, b, c) __builtin_amdgcn_mfma_f32_32x32x16_bf16((a), (b), (c), 0, 0, 0)

// async global->LDS, 16B per lane, LDS dst = wave-uniform base + lane*16
__device__ __forceinline__ void gload_lds16(const bf16* g, bf16* l) {
  __builtin_amdgcn_global_load_lds(
      (const __attribute__((address_space(1))) void*)g,
      (__attribute__((address_space(3))) void*)l, 16, 0, 0);
}

// ---------------- prep kernels ----------------

__global__ __launch_bounds__(256) void cast_bf16_kernel(
    const float* __restrict__ in, bf16* __restrict__ out, int n4) {
  int i = blockIdx.x * 256 + threadIdx.x;
  if (i < n4) {
    float4 v = reinterpret_cast<const float4*>(in)[i];
    bf16x4 o;
    o[0] = (bf16)v.x; o[1] = (bf16)v.y; o[2] = (bf16)v.z; o[3] = (bf16)v.w;
    reinterpret_cast<bf16x4*>(out)[i] = o;
  }
}

__global__ __launch_bounds__(256) void transpose_cast_kernel(
    const float* __restrict__ W, bf16* __restrict__ Wt, int K, int N) {
  __shared__ bf16 tile[64 * 66];
  const int k0 = blockIdx.y * 64, n0 = blockIdx.x * 64;
  const int c = threadIdx.x & 63, rb = threadIdx.x >> 6;
#pragma unroll
  for (int p = 0; p < 16; ++p) {
    int r = p * 4 + rb;
    tile[c * 66 + r] = (bf16)W[(long)(k0 + r) * N + n0 + c];
  }
  __syncthreads();
#pragma unroll
  for (int p = 0; p < 16; ++p) {
    int r = p * 4 + rb;
    Wt[(long)(n0 + r) * K + k0 + c] = tile[r * 66 + c];
  }
}

// ---------------- GEMM: C(M,N) = A(M,K) @ Bt(N,K)^T, m97 structure ----------------
template <int EPI>
__global__ __launch_bounds__(256, 2) void gemm_bt(
    const bf16* __restrict__ A, const bf16* __restrict__ Bt,
    const float* __restrict__ bias, bf16* __restrict__ oQ,
    bf16* __restrict__ oK, bf16* __restrict__ oVT, float* __restrict__ oC,
    int K) {
  __shared__ bf16 As[128 * 64];
  __shared__ bf16 Bs[128 * 64];
  const int tid = threadIdx.x, lane = tid & 63, wid = tid >> 6;
  const int wr = wid >> 1, wc = wid & 1;
  const int brow = blockIdx.x * 128, bcol = blockIdx.y * 128;
  const int srow = lane >> 3, scol8 = (lane & 7) * 8;
  const int c15 = lane & 15, g = lane >> 4;

  f32x4 acc[4][4];
#pragma unroll
  for (int m = 0; m < 4; ++m)
#pragma unroll
    for (int n = 0; n < 4; ++n) acc[m][n] = f32x4{0.f, 0.f, 0.f, 0.f};

  const bf16* Ab = A + (long)brow * K + scol8;
  const bf16* Bb = Bt + (long)bcol * K + scol8;

  for (int k0 = 0; k0 < K; k0 += 64) {
#pragma unroll
    for (int i = 0; i < 4; ++i) {
      int c = wid * 4 + i;
      int row = c * 8 + srow;
      gload_lds16(Ab + (long)row * K + k0, &As[c * 512]);
    }
#pragma unroll
    for (int i = 0; i < 4; ++i) {
      int c = wid * 4 + i;
      int row = c * 8 + srow;
      gload_lds16(Bb + (long)row * K + k0, &Bs[c * 512]);
    }
    __syncthreads();
#pragma unroll
    for (int kk = 0; kk < 64; kk += 32) {
      bf16x8 a[4], b[4];
#pragma unroll
      for (int m = 0; m < 4; ++m)
        a[m] = *(const bf16x8*)&As[(wr * 64 + m * 16 + c15) * 64 + kk + g * 8];
#pragma unroll
      for (int n = 0; n < 4; ++n)
        b[n] = *(const bf16x8*)&Bs[(wc * 64 + n * 16 + c15) * 64 + kk + g * 8];
#pragma unroll
      for (int m = 0; m < 4; ++m)
#pragma unroll
        for (int n = 0; n < 4; ++n)
          acc[m][n] = MFMA16(a[m], b[n], acc[m][n]);
    }
    __syncthreads();
  }

#pragma unroll
  for (int n = 0; n < 4; ++n) {
    const int col = bcol + wc * 64 + n * 16 + c15;
    const float bv = bias[col];
    if (EPI == 0) {
      const int which = col >> 10, wi = col & 1023, h = wi >> 6, d = wi & 63;
      const float sc = (which == 0) ? 0.18033688011112042f : 1.0f;  // 0.125*log2(e)
#pragma unroll
      for (int m = 0; m < 4; ++m) {
        const int row0 = brow + wr * 64 + m * 16 + g * 4;
        const int bb = row0 >> 11, t0 = row0 & 2047;
        const long hb = bb * 16 + h;
        if (which == 2) {
          bf16x4 pv;
#pragma unroll
          for (int r = 0; r < 4; ++r) pv[r] = (bf16)(acc[m][n][r] + bv);
          *(bf16x4*)&oVT[(hb * 64 + d) * 2048 + t0] = pv;  // (b,h,d,t)
        } else {
          bf16* dst = ((which == 0) ? oQ : oK) + (hb * 2048 + t0) * 64 + d;
#pragma unroll
          for (int r = 0; r < 4; ++r)
            dst[(long)r * 64] = (bf16)((acc[m][n][r] + bv) * sc);
        }
      }
    } else {
#pragma unroll
      for (int m = 0; m < 4; ++m) {
        const long row = brow + wr * 64 + m * 16 + g * 4;
#pragma unroll
        for (int r = 0; r < 4; ++r) oC[(row + r) * 1024 + col] = acc[m][n][r] + bv;
      }
    }
  }
}

// ---------------- flash attention: LDS-staged K/V, cross-block KV-split x2 ---
// Round-8 structure; round-10 fix: mask loads hoisted BEFORE the stage() issue.
// Round 8 loaded mb[] AFTER stage(t+1) -> the ballot's implicit s_waitcnt had
// to drain vmcnt to 0, killing the counted-vmcnt pipeline (12x inflation).
// Now order is: barrier / mask loads / stage(t+1) / vmcnt(6) / barrier, so the
// ballot's wait (vmcnt(4)) leaves the next tile's staging in flight.
__global__ __launch_bounds__(256, 4) void attn_kernel(
    const bf16* __restrict__ Q, const bf16* __restrict__ K,
    const bf16* __restrict__ VT, const int* __restrict__ mask,
    float* __restrict__ O_part, float* __restrict__ ml_part) {
  __shared__ bf16 Kl[2][4096];  // [buf][64 keys x 64 kdim], 8-elem groups XOR-swizzled
  __shared__ bf16 Vl[2][4096];  // [buf][64 d x 64 keys], same swizzle
  __shared__ float sws[4][32];  // rare-path rescale broadcast
  const int tid = threadIdx.x, lane = tid & 63, w = tid >> 6;
  const int col = lane & 31, hi = lane >> 5, c7 = col & 7;
  const int bid = blockIdx.x;
  const int swz = (bid & 7) * 128 + (bid >> 3);  // XCD swizzle: 4 bh per XCD
  const int bh = swz >> 5, rem = swz & 31;
  const int s = rem & 1, qb = rem >> 1;
  const int b = bh >> 4, h = bh & 15;
  const int q0 = qb * 128 + w * 32;
  const int koff0 = s * 1024;

  const bf16* Kbase = K + (long)bh * 2048 * 64;
  const bf16* Vbase = VT + (long)bh * 64 * 2048;
  const int* mb = mask + b * 2048;

  const int srow = lane >> 3;
  const int xoff = ((lane & 7) ^ srow) << 3;

  auto stage = [&](int buf, int t) {
    const int koff = koff0 + t * 64;
#pragma unroll
    for (int i = 0; i < 2; ++i) {
      const int c = w * 2 + i;
      gload_lds16(Kbase + (long)(koff + c * 8 + srow) * 64 + xoff,
                  &Kl[buf][c * 512]);
      gload_lds16(Vbase + (long)(c * 8 + srow) * 2048 + koff + xoff,
                  &Vl[buf][c * 512]);
    }
  };

  // Q B-frag (pre-scaled by 0.125*log2e in gemm epilogue)
  const bf16* Qp = Q + ((long)bh * 2048 + q0 + col) * 64 + hi * 8;
  bf16x8 bq[4];
#pragma unroll
  for (int dc = 0; dc < 4; ++dc) bq[dc] = *(const bf16x8*)(Qp + dc * 16);

  f32x16 o0, o1;
#pragma unroll
  for (int r = 0; r < 16; ++r) { o0[r] = 0.f; o1[r] = 0.f; }
  float mrun = -1e30f, lrun = 0.f;  // lrun = per-half partial until fold

  stage(0, 0);
  for (int t = 0; t < 16; ++t) {
    const int cur = t & 1;
    __builtin_amdgcn_s_barrier();  // prev tile's LDS reads done before overwrite
    // mask loads FIRST (before stage issue): ballot's wait then only needs
    // vmcnt(4), leaving next-tile staging outstanding
    const int mvA = mb[koff0 + t * 64 + col];
    const int mvB = mb[koff0 + t * 64 + 32 + col];
    if (t < 15) {
      stage(cur ^ 1, t + 1);
      // outstanding: 4 (tile t) + 2 (mask) + 4 (tile t+1) = 10 -> wait to 6
      asm volatile("s_waitcnt vmcnt(6)" ::: "memory");
    } else {
      asm volatile("s_waitcnt vmcnt(0)" ::: "memory");
    }
    __builtin_amdgcn_s_barrier();  // all waves' chunks of tile t visible

#pragma unroll
    for (int sub = 0; sub < 2; ++sub) {
      const int mv = (sub == 0) ? mvA : mvB;
      // K A-frags from LDS (swizzled groups)
      const bf16* Krow = &Kl[cur][(sub * 32 + col) * 64];
      bf16x8 ak0 = *(const bf16x8*)(Krow + (((0 + hi) ^ c7) << 3));
      bf16x8 ak1 = *(const bf16x8*)(Krow + (((2 + hi) ^ c7) << 3));
      bf16x8 ak2 = *(const bf16x8*)(Krow + (((4 + hi) ^ c7) << 3));
      bf16x8 ak3 = *(const bf16x8*)(Krow + (((6 + hi) ^ c7) << 3));
      // S^T = K @ Q^T
      f32x16 st;
#pragma unroll
      for (int r = 0; r < 16; ++r) st[r] = 0.f;
      __builtin_amdgcn_s_setprio(1);
      st = MFMA32(ak0, bq[0], st);
      st = MFMA32(ak1, bq[1], st);
      st = MFMA32(ak2, bq[2], st);
      st = MFMA32(ak3, bq[3], st);
      __builtin_amdgcn_s_setprio(0);
      // mask (wave-uniform skip when all-ones)
      unsigned km32 = (unsigned)__ballot(mv != 0);
      if (km32 != 0xffffffffu) {
        unsigned km = km32 >> (hi * 4);
#pragma unroll
        for (int r = 0; r < 16; ++r)
          if (!((km >> ((r & 3) + 8 * (r >> 2))) & 1)) st[r] = -1e30f;
      }
      // per-half row max
      float m01 = fmaxf(st[0], st[1]), m23 = fmaxf(st[2], st[3]);
      float m45 = fmaxf(st[4], st[5]), m67 = fmaxf(st[6], st[7]);
      float m89 = fmaxf(st[8], st[9]), mab = fmaxf(st[10], st[11]);
      float mcd = fmaxf(st[12], st[13]), mef = fmaxf(st[14], st[15]);
      float m0 = fmaxf(fmaxf(fmaxf(m01, m23), fmaxf(m45, m67)),
                       fmaxf(fmaxf(m89, mab), fmaxf(mcd, mef)));
      // defer-max rescale (rare)
      if (__any(m0 > mrun + 8.0f)) {
        float pm = fmaxf(m0, __shfl_xor(m0, 32));
        float mnew = fmaxf(mrun, pm);
        float scale = __builtin_exp2f(mrun - mnew);
        mrun = mnew;
        lrun *= scale;
        if (hi == 0) sws[w][col] = scale;
        asm volatile("s_waitcnt lgkmcnt(0)" ::: "memory");
#pragma unroll
        for (int r = 0; r < 16; ++r) {
          float sc = sws[w][(r & 3) + 8 * (r >> 2) + 4 * hi];
          o0[r] *= sc; o1[r] *= sc;
        }
      }
      // P = exp2(S - m) in place; per-half row-sum into lrun
#pragma unroll
      for (int r = 0; r < 16; ++r) st[r] = __builtin_exp2f(st[r] - mrun);
      float s01 = st[0] + st[1], s23 = st[2] + st[3], s45 = st[4] + st[5];
      float s67 = st[6] + st[7], s89 = st[8] + st[9], sab = st[10] + st[11];
      float scd = st[12] + st[13], sef = st[14] + st[15];
      lrun += ((s01 + s23) + (s45 + s67)) + ((s89 + sab) + (scd + sef));
      // P -> bf16 A-frags; 4 cross-half exchanges in one window
      unsigned d0, d1, d2, d3, d4, d5, d6, d7;
      {
        union { bf16 hh[2]; unsigned u; } tt;
        tt.hh[0] = (bf16)st[0];  tt.hh[1] = (bf16)st[1];  d0 = tt.u;
        tt.hh[0] = (bf16)st[2];  tt.hh[1] = (bf16)st[3];  d1 = tt.u;
        tt.hh[0] = (bf16)st[4];  tt.hh[1] = (bf16)st[5];  d2 = tt.u;
        tt.hh[0] = (bf16)st[6];  tt.hh[1] = (bf16)st[7];  d3 = tt.u;
        tt.hh[0] = (bf16)st[8];  tt.hh[1] = (bf16)st[9];  d4 = tt.u;
        tt.hh[0] = (bf16)st[10]; tt.hh[1] = (bf16)st[11]; d5 = tt.u;
        tt.hh[0] = (bf16)st[12]; tt.hh[1] = (bf16)st[13]; d6 = tt.u;
        tt.hh[0] = (bf16)st[14]; tt.hh[1] = (bf16)st[15]; d7 = tt.u;
      }
      unsigned g02 = (unsigned)__shfl_xor((int)(hi ? d0 : d2), 32);
      unsigned g13 = (unsigned)__shfl_xor((int)(hi ? d1 : d3), 32);
      unsigned g46 = (unsigned)__shfl_xor((int)(hi ? d4 : d6), 32);
      unsigned g57 = (unsigned)__shfl_xor((int)(hi ? d5 : d7), 32);
      u32x4 w0 = {hi ? g02 : d0, hi ? g13 : d1, hi ? d2 : g02, hi ? d3 : g13};
      u32x4 w1 = {hi ? g46 : d4, hi ? g57 : d5, hi ? d6 : g46, hi ? d7 : g57};
      bf16x8 pa0 = __builtin_bit_cast(bf16x8, w0);
      bf16x8 pa1 = __builtin_bit_cast(bf16x8, w1);
      // V B-frags from LDS
      const bf16* Vrow0 = &Vl[cur][col * 64];
      const bf16* Vrow1 = &Vl[cur][(col + 32) * 64];
      const int g0 = ((sub * 4 + hi) ^ c7) << 3;
      const int g1 = ((sub * 4 + 2 + hi) ^ c7) << 3;
      bf16x8 bv00 = *(const bf16x8*)(Vrow0 + g0);
      bf16x8 bv10 = *(const bf16x8*)(Vrow0 + g1);
      bf16x8 bv01 = *(const bf16x8*)(Vrow1 + g0);
      bf16x8 bv11 = *(const bf16x8*)(Vrow1 + g1);
      // O += P @ V
      __builtin_amdgcn_s_setprio(1);
      o0 = MFMA32(pa0, bv00, o0);
      o0 = MFMA32(pa1, bv10, o0);
      o1 = MFMA32(pa0, bv01, o1);
      o1 = MFMA32(pa1, bv11, o1);
      __builtin_amdgcn_s_setprio(0);
    }
  }

  // ---- write raw partial (O, m, l) for cross-block merge ----
  lrun += __shfl_xor(lrun, 32);  // fold per-half l partials
  if (hi == 0) {
    float2 v; v.x = mrun; v.y = lrun;
    *(float2*)&ml_part[((long)s * 65536 + bh * 2048 + q0 + col) * 2] = v;
  }
  float* Os = O_part + (long)s * 4194304;
#pragma unroll
  for (int r = 0; r < 16; ++r) {
    const int qr = (r & 3) + 8 * (r >> 2) + 4 * hi;
    long base = ((long)b * 2048 + q0 + qr) * 1024 + h * 64 + col;
    Os[base] = o0[r];
    Os[base + 32] = o1[r];
  }
}

// ---------------- merge the 2 KV-split partials -> Aatt (bf16) ---------------
__global__ __launch_bounds__(256) void attn_merge_kernel(
    const float* __restrict__ O_part, const float* __restrict__ ml_part,
    bf16* __restrict__ Aout) {
  const int i = blockIdx.x * 256 + threadIdx.x;  // float4 group over 4096x1024
  const int qg = i >> 8;                         // global query row
  const int h = (i & 255) >> 4;
  const int bq = qg >> 11, t = qg & 2047;
  const int bh = bq * 16 + h;
  const float2 ml0 = *(const float2*)&ml_part[((long)bh * 2048 + t) * 2];
  const float2 ml1 = *(const float2*)&ml_part[((long)65536 + bh * 2048 + t) * 2];
  const float ms = fmaxf(ml0.x, ml1.x);
  const float w0 = __builtin_exp2f(ml0.x - ms);
  const float w1 = __builtin_exp2f(ml1.x - ms);
  const float inv = 1.0f / (w0 * ml0.y + w1 * ml1.y);
  float4 a = ((const float4*)O_part)[i];
  float4 c = ((const float4*)(O_part + 4194304))[i];
  bf16x4 o;
  o[0] = (bf16)((w0 * a.x + w1 * c.x) * inv);
  o[1] = (bf16)((w0 * a.y + w1 * c.y) * inv);
  o[2] = (bf16)((w0 * a.z + w1 * c.z) * inv);
  o[3] = (bf16)((w0 * a.w + w1 * c.w) * inv);
  ((bf16x4*)Aout)[i] = o;
}

// ---------------- launcher ----------------
extern "C" void kernel_launch(void* const* d_in, const int* in_sizes, int n_in,
                              void* d_out, int out_size, void* d_ws,
                              size_t ws_size, hipStream_t stream) {
  const float* x    = (const float*)d_in[0];
  const int*   mask = (const int*)d_in[1];
  const float* Wqkv = (const float*)d_in[2];
  const float* bqkv = (const float*)d_in[3];
  const float* Wout = (const float*)d_in[4];
  const float* bout = (const float*)d_in[5];
  float* out = (float*)d_out;

  char* ws = (char*)d_ws;
  bf16* xb    = (bf16*)(ws);                      // 8 MB; reused as Aatt
  bf16* wqkvT = (bf16*)(ws + (8u << 20));         // 6 MB
  bf16* woutT = (bf16*)(ws + (14u << 20));        // 2 MB
  bf16* Qb    = (bf16*)(ws + (16u << 20));        // 8 MB (b,h,t,d)
  bf16* Kb    = (bf16*)(ws + (24u << 20));        // 8 MB (b,h,t,d)
  bf16* VTb   = (bf16*)(ws + (32u << 20));        // 8 MB (b,h,d,t)
  float* Opart = (float*)(ws + (40u << 20));      // 32 MB (2 splits, fp32)
  float* mlp   = (float*)(ws + (72u << 20));      // 1 MB
  bf16* Aatt  = xb;

  cast_bf16_kernel<<<4096, 256, 0, stream>>>(x, xb, (4096 * 1024) / 4);
  transpose_cast_kernel<<<dim3(48, 16), 256, 0, stream>>>(Wqkv, wqkvT, 1024, 3072);
  transpose_cast_kernel<<<dim3(16, 16), 256, 0, stream>>>(Wout, woutT, 1024, 1024);
  gemm_bt<0><<<dim3(32, 24), 256, 0, stream>>>(xb, wqkvT, bqkv, Qb, Kb, VTb,
                                               nullptr, 1024);
  attn_kernel<<<1024, 256, 0, stream>>>(Qb, Kb, VTb, mask, Opart, mlp);
  attn_merge_kernel<<<4096, 256, 0, stream>>>(Opart, mlp, Aatt);
  gemm_bt<1><<<dim3(32, 8), 256, 0, stream>>>(Aatt, woutT, bout, nullptr,
                                              nullptr, nullptr, out, 1024);
}

// Round 11
// 137.970 us; speedup vs baseline: 1.4567x; 1.2614x over previous
//
#include <hip/hip_runtime.h>

typedef __bf16 bf16;
typedef __bf16 bf16x8 __attribute__((ext_vector_type(8)));
typedef __bf16 bf16x4 __attribute__((ext_vector_type(4)));
typedef float  f32x4  __attribute__((ext_vector_type(4)));
typedef float  f32x16 __attribute__((ext_vector_type(16)));
typedef unsigned int u32x4 __attribute__((ext_vector_type(4)));

#define MFMA16(a, b, c) __builtin_amdgcn_mfma_f32_16x16x32_bf16((a), (b), (c), 0, 0, 0)
#define MFMA32(a, b, c) __builtin_amdgcn_mfma_f32_32x32x16_bf16((a), (b), (c), 0, 0, 0)

// raw v_exp_f32: skips LLVM's denormal-range fixup (~6 insts -> 1).
// Safe here: masked scores (-1e30) -> 0; sub-denormal P flushes to 0.
__device__ __forceinline__ float fexp2(float x) {
  return __builtin_amdgcn_exp2f(x);
}

// packed f32x2 -> bf16x2 in one HW op (RNE), replaces 2 casts + pack
__device__ __forceinline__ unsigned cvt_pk_bf16(float lo, float hi) {
  unsigned r;
  asm("v_cvt_pk_bf16_f32 %0, %1, %2" : "=v"(r) : "v"(lo), "v"(hi));
  return r;
}

// async global->LDS, 16B per lane, LDS dst = wave-uniform base + lane*16
__device__ __forceinline__ void gload_lds16(const bf16* g, bf16* l) {
  __builtin_amdgcn_global_load_lds(
      (const __attribute__((address_space(1))) void*)g,
      (__attribute__((address_space(3))) void*)l, 16, 0, 0);
}

// ---------------- prep kernels ----------------

__global__ __launch_bounds__(256) void cast_bf16_kernel(
    const float* __restrict__ in, bf16* __restrict__ out, int n4) {
  int i = blockIdx.x * 256 + threadIdx.x;
  if (i < n4) {
    float4 v = reinterpret_cast<const float4*>(in)[i];
    bf16x4 o;
    o[0] = (bf16)v.x; o[1] = (bf16)v.y; o[2] = (bf16)v.z; o[3] = (bf16)v.w;
    reinterpret_cast<bf16x4*>(out)[i] = o;
  }
}

__global__ __launch_bounds__(256) void transpose_cast_kernel(
    const float* __restrict__ W, bf16* __restrict__ Wt, int K, int N) {
  __shared__ bf16 tile[64 * 66];
  const int k0 = blockIdx.y * 64, n0 = blockIdx.x * 64;
  const int c = threadIdx.x & 63, rb = threadIdx.x >> 6;
#pragma unroll
  for (int p = 0; p < 16; ++p) {
    int r = p * 4 + rb;
    tile[c * 66 + r] = (bf16)W[(long)(k0 + r) * N + n0 + c];
  }
  __syncthreads();
#pragma unroll
  for (int p = 0; p < 16; ++p) {
    int r = p * 4 + rb;
    Wt[(long)(n0 + r) * K + k0 + c] = tile[r * 66 + c];
  }
}

// ---------------- GEMM: C(M,N) = A(M,K) @ Bt(N,K)^T, m97 structure ----------------
template <int EPI>
__global__ __launch_bounds__(256, 2) void gemm_bt(
    const bf16* __restrict__ A, const bf16* __restrict__ Bt,
    const float* __restrict__ bias, bf16* __restrict__ oQ,
    bf16* __restrict__ oK, bf16* __restrict__ oVT, float* __restrict__ oC,
    int K) {
  __shared__ bf16 As[128 * 64];
  __shared__ bf16 Bs[128 * 64];
  const int tid = threadIdx.x, lane = tid & 63, wid = tid >> 6;
  const int wr = wid >> 1, wc = wid & 1;
  const int brow = blockIdx.x * 128, bcol = blockIdx.y * 128;
  const int srow = lane >> 3, scol8 = (lane & 7) * 8;
  const int c15 = lane & 15, g = lane >> 4;

  f32x4 acc[4][4];
#pragma unroll
  for (int m = 0; m < 4; ++m)
#pragma unroll
    for (int n = 0; n < 4; ++n) acc[m][n] = f32x4{0.f, 0.f, 0.f, 0.f};

  const bf16* Ab = A + (long)brow * K + scol8;
  const bf16* Bb = Bt + (long)bcol * K + scol8;

  for (int k0 = 0; k0 < K; k0 += 64) {
#pragma unroll
    for (int i = 0; i < 4; ++i) {
      int c = wid * 4 + i;
      int row = c * 8 + srow;
      gload_lds16(Ab + (long)row * K + k0, &As[c * 512]);
    }
#pragma unroll
    for (int i = 0; i < 4; ++i) {
      int c = wid * 4 + i;
      int row = c * 8 + srow;
      gload_lds16(Bb + (long)row * K + k0, &Bs[c * 512]);
    }
    __syncthreads();
#pragma unroll
    for (int kk = 0; kk < 64; kk += 32) {
      bf16x8 a[4], b[4];
#pragma unroll
      for (int m = 0; m < 4; ++m)
        a[m] = *(const bf16x8*)&As[(wr * 64 + m * 16 + c15) * 64 + kk + g * 8];
#pragma unroll
      for (int n = 0; n < 4; ++n)
        b[n] = *(const bf16x8*)&Bs[(wc * 64 + n * 16 + c15) * 64 + kk + g * 8];
#pragma unroll
      for (int m = 0; m < 4; ++m)
#pragma unroll
        for (int n = 0; n < 4; ++n)
          acc[m][n] = MFMA16(a[m], b[n], acc[m][n]);
    }
    __syncthreads();
  }

#pragma unroll
  for (int n = 0; n < 4; ++n) {
    const int col = bcol + wc * 64 + n * 16 + c15;
    const float bv = bias[col];
    if (EPI == 0) {
      const int which = col >> 10, wi = col & 1023, h = wi >> 6, d = wi & 63;
      const float sc = (which == 0) ? 0.18033688011112042f : 1.0f;  // 0.125*log2(e)
#pragma unroll
      for (int m = 0; m < 4; ++m) {
        const int row0 = brow + wr * 64 + m * 16 + g * 4;
        const int bb = row0 >> 11, t0 = row0 & 2047;
        const long hb = bb * 16 + h;
        if (which == 2) {
          bf16x4 pv;
#pragma unroll
          for (int r = 0; r < 4; ++r) pv[r] = (bf16)(acc[m][n][r] + bv);
          *(bf16x4*)&oVT[(hb * 64 + d) * 2048 + t0] = pv;  // (b,h,d,t)
        } else {
          bf16* dst = ((which == 0) ? oQ : oK) + (hb * 2048 + t0) * 64 + d;
#pragma unroll
          for (int r = 0; r < 4; ++r)
            dst[(long)r * 64] = (bf16)((acc[m][n][r] + bv) * sc);
        }
      }
    } else {
#pragma unroll
      for (int m = 0; m < 4; ++m) {
        const long row = brow + wr * 64 + m * 16 + g * 4;
#pragma unroll
        for (int r = 0; r < 4; ++r) oC[(row + r) * 1024 + col] = acc[m][n][r] + bv;
      }
    }
  }
}

// ---------------- flash attention: LDS-staged K/V, cross-block KV-split x2 ---
// Round-10 structure. Round-11: VALU de-bloat only -- raw v_exp_f32 (no
// denormal fixup: ~6 insts -> 1) and v_cvt_pk_bf16_f32 for the P pack
// (~24 insts -> 8). Counter calibration showed ~530 VALU insts/subtile vs
// ~110 hand-counted; exp2 fixup + bfloat cast lowering were the bloat.
__global__ __launch_bounds__(256, 4) void attn_kernel(
    const bf16* __restrict__ Q, const bf16* __restrict__ K,
    const bf16* __restrict__ VT, const int* __restrict__ mask,
    float* __restrict__ O_part, float* __restrict__ ml_part) {
  __shared__ bf16 Kl[2][4096];  // [buf][64 keys x 64 kdim], 8-elem groups XOR-swizzled
  __shared__ bf16 Vl[2][4096];  // [buf][64 d x 64 keys], same swizzle
  __shared__ float sws[4][32];  // rare-path rescale broadcast
  const int tid = threadIdx.x, lane = tid & 63, w = tid >> 6;
  const int col = lane & 31, hi = lane >> 5, c7 = col & 7;
  const int bid = blockIdx.x;
  const int swz = (bid & 7) * 128 + (bid >> 3);  // XCD swizzle: 4 bh per XCD
  const int bh = swz >> 5, rem = swz & 31;
  const int s = rem & 1, qb = rem >> 1;
  const int b = bh >> 4, h = bh & 15;
  const int q0 = qb * 128 + w * 32;
  const int koff0 = s * 1024;

  const bf16* Kbase = K + (long)bh * 2048 * 64;
  const bf16* Vbase = VT + (long)bh * 64 * 2048;
  const int* mb = mask + b * 2048;

  const int srow = lane >> 3;
  const int xoff = ((lane & 7) ^ srow) << 3;

  auto stage = [&](int buf, int t) {
    const int koff = koff0 + t * 64;
#pragma unroll
    for (int i = 0; i < 2; ++i) {
      const int c = w * 2 + i;
      gload_lds16(Kbase + (long)(koff + c * 8 + srow) * 64 + xoff,
                  &Kl[buf][c * 512]);
      gload_lds16(Vbase + (long)(c * 8 + srow) * 2048 + koff + xoff,
                  &Vl[buf][c * 512]);
    }
  };

  // Q B-frag (pre-scaled by 0.125*log2e in gemm epilogue)
  const bf16* Qp = Q + ((long)bh * 2048 + q0 + col) * 64 + hi * 8;
  bf16x8 bq[4];
#pragma unroll
  for (int dc = 0; dc < 4; ++dc) bq[dc] = *(const bf16x8*)(Qp + dc * 16);

  f32x16 o0, o1;
#pragma unroll
  for (int r = 0; r < 16; ++r) { o0[r] = 0.f; o1[r] = 0.f; }
  float mrun = -1e30f, lrun = 0.f;  // lrun = per-half partial until fold

  stage(0, 0);
  for (int t = 0; t < 16; ++t) {
    const int cur = t & 1;
    __builtin_amdgcn_s_barrier();  // prev tile's LDS reads done before overwrite
    // mask loads FIRST (before stage issue): ballot's wait leaves staging in flight
    const int mvA = mb[koff0 + t * 64 + col];
    const int mvB = mb[koff0 + t * 64 + 32 + col];
    if (t < 15) {
      stage(cur ^ 1, t + 1);
      // outstanding: 4 (tile t) + 2 (mask) + 4 (tile t+1) = 10 -> wait to 6
      asm volatile("s_waitcnt vmcnt(6)" ::: "memory");
    } else {
      asm volatile("s_waitcnt vmcnt(0)" ::: "memory");
    }
    __builtin_amdgcn_s_barrier();  // all waves' chunks of tile t visible

#pragma unroll
    for (int sub = 0; sub < 2; ++sub) {
      const int mv = (sub == 0) ? mvA : mvB;
      // K A-frags from LDS (swizzled groups)
      const bf16* Krow = &Kl[cur][(sub * 32 + col) * 64];
      bf16x8 ak0 = *(const bf16x8*)(Krow + (((0 + hi) ^ c7) << 3));
      bf16x8 ak1 = *(const bf16x8*)(Krow + (((2 + hi) ^ c7) << 3));
      bf16x8 ak2 = *(const bf16x8*)(Krow + (((4 + hi) ^ c7) << 3));
      bf16x8 ak3 = *(const bf16x8*)(Krow + (((6 + hi) ^ c7) << 3));
      // S^T = K @ Q^T
      f32x16 st;
#pragma unroll
      for (int r = 0; r < 16; ++r) st[r] = 0.f;
      __builtin_amdgcn_s_setprio(1);
      st = MFMA32(ak0, bq[0], st);
      st = MFMA32(ak1, bq[1], st);
      st = MFMA32(ak2, bq[2], st);
      st = MFMA32(ak3, bq[3], st);
      __builtin_amdgcn_s_setprio(0);
      // mask (wave-uniform skip when all-ones)
      unsigned km32 = (unsigned)__ballot(mv != 0);
      if (km32 != 0xffffffffu) {
        unsigned km = km32 >> (hi * 4);
#pragma unroll
        for (int r = 0; r < 16; ++r)
          if (!((km >> ((r & 3) + 8 * (r >> 2))) & 1)) st[r] = -1e30f;
      }
      // per-half row max
      float m01 = fmaxf(st[0], st[1]), m23 = fmaxf(st[2], st[3]);
      float m45 = fmaxf(st[4], st[5]), m67 = fmaxf(st[6], st[7]);
      float m89 = fmaxf(st[8], st[9]), mab = fmaxf(st[10], st[11]);
      float mcd = fmaxf(st[12], st[13]), mef = fmaxf(st[14], st[15]);
      float m0 = fmaxf(fmaxf(fmaxf(m01, m23), fmaxf(m45, m67)),
                       fmaxf(fmaxf(m89, mab), fmaxf(mcd, mef)));
      // defer-max rescale (rare)
      if (__any(m0 > mrun + 8.0f)) {
        float pm = fmaxf(m0, __shfl_xor(m0, 32));
        float mnew = fmaxf(mrun, pm);
        float scale = fexp2(mrun - mnew);
        mrun = mnew;
        lrun *= scale;
        if (hi == 0) sws[w][col] = scale;
        asm volatile("s_waitcnt lgkmcnt(0)" ::: "memory");
#pragma unroll
        for (int r = 0; r < 16; ++r) {
          float sc = sws[w][(r & 3) + 8 * (r >> 2) + 4 * hi];
          o0[r] *= sc; o1[r] *= sc;
        }
      }
      // P = exp2(S - m) in place (raw v_exp_f32); per-half row-sum into lrun
#pragma unroll
      for (int r = 0; r < 16; ++r) st[r] = fexp2(st[r] - mrun);
      float s01 = st[0] + st[1], s23 = st[2] + st[3], s45 = st[4] + st[5];
      float s67 = st[6] + st[7], s89 = st[8] + st[9], sab = st[10] + st[11];
      float scd = st[12] + st[13], sef = st[14] + st[15];
      lrun += ((s01 + s23) + (s45 + s67)) + ((s89 + sab) + (scd + sef));
      // P -> bf16 A-frags: 8 cvt_pk + 4 cross-half exchanges in one window
      unsigned d0 = cvt_pk_bf16(st[0], st[1]);
      unsigned d1 = cvt_pk_bf16(st[2], st[3]);
      unsigned d2 = cvt_pk_bf16(st[4], st[5]);
      unsigned d3 = cvt_pk_bf16(st[6], st[7]);
      unsigned d4 = cvt_pk_bf16(st[8], st[9]);
      unsigned d5 = cvt_pk_bf16(st[10], st[11]);
      unsigned d6 = cvt_pk_bf16(st[12], st[13]);
      unsigned d7 = cvt_pk_bf16(st[14], st[15]);
      unsigned g02 = (unsigned)__shfl_xor((int)(hi ? d0 : d2), 32);
      unsigned g13 = (unsigned)__shfl_xor((int)(hi ? d1 : d3), 32);
      unsigned g46 = (unsigned)__shfl_xor((int)(hi ? d4 : d6), 32);
      unsigned g57 = (unsigned)__shfl_xor((int)(hi ? d5 : d7), 32);
      u32x4 w0 = {hi ? g02 : d0, hi ? g13 : d1, hi ? d2 : g02, hi ? d3 : g13};
      u32x4 w1 = {hi ? g46 : d4, hi ? g57 : d5, hi ? d6 : g46, hi ? d7 : g57};
      bf16x8 pa0 = __builtin_bit_cast(bf16x8, w0);
      bf16x8 pa1 = __builtin_bit_cast(bf16x8, w1);
      // V B-frags from LDS
      const bf16* Vrow0 = &Vl[cur][col * 64];
      const bf16* Vrow1 = &Vl[cur][(col + 32) * 64];
      const int g0 = ((sub * 4 + hi) ^ c7) << 3;
      const int g1 = ((sub * 4 + 2 + hi) ^ c7) << 3;
      bf16x8 bv00 = *(const bf16x8*)(Vrow0 + g0);
      bf16x8 bv10 = *(const bf16x8*)(Vrow0 + g1);
      bf16x8 bv01 = *(const bf16x8*)(Vrow1 + g0);
      bf16x8 bv11 = *(const bf16x8*)(Vrow1 + g1);
      // O += P @ V
      __builtin_amdgcn_s_setprio(1);
      o0 = MFMA32(pa0, bv00, o0);
      o0 = MFMA32(pa1, bv10, o0);
      o1 = MFMA32(pa0, bv01, o1);
      o1 = MFMA32(pa1, bv11, o1);
      __builtin_amdgcn_s_setprio(0);
    }
  }

  // ---- write raw partial (O, m, l) for cross-block merge ----
  lrun += __shfl_xor(lrun, 32);  // fold per-half l partials
  if (hi == 0) {
    float2 v; v.x = mrun; v.y = lrun;
    *(float2*)&ml_part[((long)s * 65536 + bh * 2048 + q0 + col) * 2] = v;
  }
  float* Os = O_part + (long)s * 4194304;
#pragma unroll
  for (int r = 0; r < 16; ++r) {
    const int qr = (r & 3) + 8 * (r >> 2) + 4 * hi;
    long base = ((long)b * 2048 + q0 + qr) * 1024 + h * 64 + col;
    Os[base] = o0[r];
    Os[base + 32] = o1[r];
  }
}

// ---------------- merge the 2 KV-split partials -> Aatt (bf16) ---------------
__global__ __launch_bounds__(256) void attn_merge_kernel(
    const float* __restrict__ O_part, const float* __restrict__ ml_part,
    bf16* __restrict__ Aout) {
  const int i = blockIdx.x * 256 + threadIdx.x;  // float4 group over 4096x1024
  const int qg = i >> 8;                         // global query row
  const int h = (i & 255) >> 4;
  const int bq = qg >> 11, t = qg & 2047;
  const int bh = bq * 16 + h;
  const float2 ml0 = *(const float2*)&ml_part[((long)bh * 2048 + t) * 2];
  const float2 ml1 = *(const float2*)&ml_part[((long)65536 + bh * 2048 + t) * 2];
  const float ms = fmaxf(ml0.x, ml1.x);
  const float w0 = fexp2(ml0.x - ms);
  const float w1 = fexp2(ml1.x - ms);
  const float inv = 1.0f / (w0 * ml0.y + w1 * ml1.y);
  float4 a = ((const float4*)O_part)[i];
  float4 c = ((const float4*)(O_part + 4194304))[i];
  bf16x4 o;
  o[0] = (bf16)((w0 * a.x + w1 * c.x) * inv);
  o[1] = (bf16)((w0 * a.y + w1 * c.y) * inv);
  o[2] = (bf16)((w0 * a.z + w1 * c.z) * inv);
  o[3] = (bf16)((w0 * a.w + w1 * c.w) * inv);
  ((bf16x4*)Aout)[i] = o;
}

// ---------------- launcher ----------------
extern "C" void kernel_launch(void* const* d_in, const int* in_sizes, int n_in,
                              void* d_out, int out_size, void* d_ws,
                              size_t ws_size, hipStream_t stream) {
  const float* x    = (const float*)d_in[0];
  const int*   mask = (const int*)d_in[1];
  const float* Wqkv = (const float*)d_in[2];
  const float* bqkv = (const float*)d_in[3];
  const float* Wout = (const float*)d_in[4];
  const float* bout = (const float*)d_in[5];
  float* out = (float*)d_out;

  char* ws = (char*)d_ws;
  bf16* xb    = (bf16*)(ws);                      // 8 MB; reused as Aatt
  bf16* wqkvT = (bf16*)(ws + (8u << 20));         // 6 MB
  bf16* woutT = (bf16*)(ws + (14u << 20));        // 2 MB
  bf16* Qb    = (bf16*)(ws + (16u << 20));        // 8 MB (b,h,t,d)
  bf16* Kb    = (bf16*)(ws + (24u << 20));        // 8 MB (b,h,t,d)
  bf16* VTb   = (bf16*)(ws + (32u << 20));        // 8 MB (b,h,d,t)
  float* Opart = (float*)(ws + (40u << 20));      // 32 MB (2 splits, fp32)
  float* mlp   = (float*)(ws + (72u << 20));      // 1 MB
  bf16* Aatt  = xb;

  cast_bf16_kernel<<<4096, 256, 0, stream>>>(x, xb, (4096 * 1024) / 4);
  transpose_cast_kernel<<<dim3(48, 16), 256, 0, stream>>>(Wqkv, wqkvT, 1024, 3072);
  transpose_cast_kernel<<<dim3(16, 16), 256, 0, stream>>>(Wout, woutT, 1024, 1024);
  gemm_bt<0><<<dim3(32, 24), 256, 0, stream>>>(xb, wqkvT, bqkv, Qb, Kb, VTb,
                                               nullptr, 1024);
  attn_kernel<<<1024, 256, 0, stream>>>(Qb, Kb, VTb, mask, Opart, mlp);
  attn_merge_kernel<<<4096, 256, 0, stream>>>(Opart, mlp, Aatt);
  gemm_bt<1><<<dim3(32, 8), 256, 0, stream>>>(Aatt, woutT, bout, nullptr,
                                              nullptr, nullptr, out, 1024);
}

// Round 12
// 133.116 us; speedup vs baseline: 1.5098x; 1.0365x over previous
//
#include <hip/hip_runtime.h>

typedef __bf16 bf16;
typedef __bf16 bf16x8 __attribute__((ext_vector_type(8)));
typedef __bf16 bf16x4 __attribute__((ext_vector_type(4)));
typedef float  f32x4  __attribute__((ext_vector_type(4)));
typedef float  f32x16 __attribute__((ext_vector_type(16)));
typedef unsigned int u32x4 __attribute__((ext_vector_type(4)));

#define MFMA16(a, b, c) __builtin_amdgcn_mfma_f32_16x16x32_bf16((a), (b), (c), 0, 0, 0)
#define MFMA32(a, b, c) __builtin_amdgcn_mfma_f32_32x32x16_bf16((a), (b), (c), 0, 0, 0)

// raw v_exp_f32: skips LLVM's denormal-range fixup (~6 insts -> 1)
__device__ __forceinline__ float fexp2(float x) {
  return __builtin_amdgcn_exp2f(x);
}

// packed f32x2 -> bf16x2 in one HW op (RNE)
__device__ __forceinline__ unsigned cvt_pk_bf16(float lo, float hi) {
  unsigned r;
  asm("v_cvt_pk_bf16_f32 %0, %1, %2" : "=v"(r) : "v"(lo), "v"(hi));
  return r;
}

// async global->LDS, 16B per lane, LDS dst = wave-uniform base + lane*16
__device__ __forceinline__ void gload_lds16(const bf16* g, bf16* l) {
  __builtin_amdgcn_global_load_lds(
      (const __attribute__((address_space(1))) void*)g,
      (__attribute__((address_space(3))) void*)l, 16, 0, 0);
}

// ---------------- prep kernels ----------------

__global__ __launch_bounds__(256) void cast_bf16_kernel(
    const float* __restrict__ in, bf16* __restrict__ out, int n4) {
  int i = blockIdx.x * 256 + threadIdx.x;
  if (i < n4) {
    float4 v = reinterpret_cast<const float4*>(in)[i];
    bf16x4 o;
    o[0] = (bf16)v.x; o[1] = (bf16)v.y; o[2] = (bf16)v.z; o[3] = (bf16)v.w;
    reinterpret_cast<bf16x4*>(out)[i] = o;
  }
}

__global__ __launch_bounds__(256) void transpose_cast_kernel(
    const float* __restrict__ W, bf16* __restrict__ Wt, int K, int N) {
  __shared__ bf16 tile[64 * 66];
  const int k0 = blockIdx.y * 64, n0 = blockIdx.x * 64;
  const int c = threadIdx.x & 63, rb = threadIdx.x >> 6;
#pragma unroll
  for (int p = 0; p < 16; ++p) {
    int r = p * 4 + rb;
    tile[c * 66 + r] = (bf16)W[(long)(k0 + r) * N + n0 + c];
  }
  __syncthreads();
#pragma unroll
  for (int p = 0; p < 16; ++p) {
    int r = p * 4 + rb;
    Wt[(long)(n0 + r) * K + k0 + c] = tile[r * 66 + c];
  }
}

// ---------------- GEMM: C(M,N) = A(M,K) @ Bt(N,K)^T, m97 structure ----------------
template <int EPI>
__global__ __launch_bounds__(256, 2) void gemm_bt(
    const bf16* __restrict__ A, const bf16* __restrict__ Bt,
    const float* __restrict__ bias, bf16* __restrict__ oQ,
    bf16* __restrict__ oK, bf16* __restrict__ oVT, float* __restrict__ oC,
    int K) {
  __shared__ bf16 As[128 * 64];
  __shared__ bf16 Bs[128 * 64];
  const int tid = threadIdx.x, lane = tid & 63, wid = tid >> 6;
  const int wr = wid >> 1, wc = wid & 1;
  const int brow = blockIdx.x * 128, bcol = blockIdx.y * 128;
  const int srow = lane >> 3, scol8 = (lane & 7) * 8;
  const int c15 = lane & 15, g = lane >> 4;

  f32x4 acc[4][4];
#pragma unroll
  for (int m = 0; m < 4; ++m)
#pragma unroll
    for (int n = 0; n < 4; ++n) acc[m][n] = f32x4{0.f, 0.f, 0.f, 0.f};

  const bf16* Ab = A + (long)brow * K + scol8;
  const bf16* Bb = Bt + (long)bcol * K + scol8;

  for (int k0 = 0; k0 < K; k0 += 64) {
#pragma unroll
    for (int i = 0; i < 4; ++i) {
      int c = wid * 4 + i;
      int row = c * 8 + srow;
      gload_lds16(Ab + (long)row * K + k0, &As[c * 512]);
    }
#pragma unroll
    for (int i = 0; i < 4; ++i) {
      int c = wid * 4 + i;
      int row = c * 8 + srow;
      gload_lds16(Bb + (long)row * K + k0, &Bs[c * 512]);
    }
    __syncthreads();
#pragma unroll
    for (int kk = 0; kk < 64; kk += 32) {
      bf16x8 a[4], b[4];
#pragma unroll
      for (int m = 0; m < 4; ++m)
        a[m] = *(const bf16x8*)&As[(wr * 64 + m * 16 + c15) * 64 + kk + g * 8];
#pragma unroll
      for (int n = 0; n < 4; ++n)
        b[n] = *(const bf16x8*)&Bs[(wc * 64 + n * 16 + c15) * 64 + kk + g * 8];
#pragma unroll
      for (int m = 0; m < 4; ++m)
#pragma unroll
        for (int n = 0; n < 4; ++n)
          acc[m][n] = MFMA16(a[m], b[n], acc[m][n]);
    }
    __syncthreads();
  }

#pragma unroll
  for (int n = 0; n < 4; ++n) {
    const int col = bcol + wc * 64 + n * 16 + c15;
    const float bv = bias[col];
    if (EPI == 0) {
      const int which = col >> 10, wi = col & 1023, h = wi >> 6, d = wi & 63;
      const float sc = (which == 0) ? 0.18033688011112042f : 1.0f;  // 0.125*log2(e)
#pragma unroll
      for (int m = 0; m < 4; ++m) {
        const int row0 = brow + wr * 64 + m * 16 + g * 4;
        const int bb = row0 >> 11, t0 = row0 & 2047;
        const long hb = bb * 16 + h;
        if (which == 2) {
          bf16x4 pv;
#pragma unroll
          for (int r = 0; r < 4; ++r) pv[r] = (bf16)(acc[m][n][r] + bv);
          *(bf16x4*)&oVT[(hb * 64 + d) * 2048 + t0] = pv;  // (b,h,d,t)
        } else {
          bf16* dst = ((which == 0) ? oQ : oK) + (hb * 2048 + t0) * 64 + d;
#pragma unroll
          for (int r = 0; r < 4; ++r)
            dst[(long)r * 64] = (bf16)((acc[m][n][r] + bv) * sc);
        }
      }
    } else {
#pragma unroll
      for (int m = 0; m < 4; ++m) {
        const long row = brow + wr * 64 + m * 16 + g * 4;
#pragma unroll
        for (int r = 0; r < 4; ++r) oC[(row + r) * 1024 + col] = acc[m][n][r] + bv;
      }
    }
  }
}

// ---------------- flash attention: staged K/V, IN-BLOCK KV-split x2 ----------
// 512 blocks x 8 waves (512 thr). Waves w&3 own q-group (4 x 32 queries);
// w>>2 = KV-half (2 independent staging streams, identical tile counts so
// block barriers stay aligned). Round-12 change: the 2-split merge moved from
// a separate kernel + 64MB global round-trip into LDS (split-1 waves park O
// in the dead K-staging buffers; split-0 waves merge fp32 and store bf16).
__global__ __launch_bounds__(512, 4) void attn_kernel(
    const bf16* __restrict__ Q, const bf16* __restrict__ K,
    const bf16* __restrict__ VT, const int* __restrict__ mask,
    bf16* __restrict__ Aout) {
  __shared__ bf16 Kl[2][2][4096];   // [stream][buf][64 keys x 64 kdim], XOR-swz (32 KB)
  __shared__ bf16 Vl[2][2][4096];   // [stream][buf][64 d x 64 keys] (32 KB)
  __shared__ float sws[8][32];      // rare-path rescale broadcast
  __shared__ float mlL[2][4][2][32];// [split][q-group][{m,l}][query]
  const int tid = threadIdx.x, lane = tid & 63, w = tid >> 6;
  const int wq = w & 3, s = w >> 2;
  const int col = lane & 31, hi = lane >> 5, c7 = col & 7;
  const int bid = blockIdx.x;
  const int swz = (bid & 7) * 64 + (bid >> 3);  // XCD swizzle (512 % 8 == 0)
  const int bh = swz >> 4, qb = swz & 15;
  const int b = bh >> 4, h = bh & 15;
  const int q0 = qb * 128 + wq * 32;
  const int koff0 = s * 1024;

  const bf16* Kbase = K + (long)bh * 2048 * 64;
  const bf16* Vbase = VT + (long)bh * 64 * 2048;
  const int* mb = mask + b * 2048;

  const int srow = lane >> 3;
  const int xoff = ((lane & 7) ^ srow) << 3;

  auto stage = [&](int buf, int t) {
    const int koff = koff0 + t * 64;
#pragma unroll
    for (int i = 0; i < 2; ++i) {
      const int c = wq * 2 + i;
      gload_lds16(Kbase + (long)(koff + c * 8 + srow) * 64 + xoff,
                  &Kl[s][buf][c * 512]);
      gload_lds16(Vbase + (long)(c * 8 + srow) * 2048 + koff + xoff,
                  &Vl[s][buf][c * 512]);
    }
  };

  // Q B-frag (pre-scaled by 0.125*log2e in gemm epilogue)
  const bf16* Qp = Q + ((long)bh * 2048 + q0 + col) * 64 + hi * 8;
  bf16x8 bq[4];
#pragma unroll
  for (int dc = 0; dc < 4; ++dc) bq[dc] = *(const bf16x8*)(Qp + dc * 16);

  f32x16 o0, o1;
#pragma unroll
  for (int r = 0; r < 16; ++r) { o0[r] = 0.f; o1[r] = 0.f; }
  float mrun = -1e30f, lrun = 0.f;  // lrun = per-half partial until fold

  stage(0, 0);
  for (int t = 0; t < 16; ++t) {
    const int cur = t & 1;
    __builtin_amdgcn_s_barrier();  // prev tile's LDS reads done before overwrite
    const int mvA = mb[koff0 + t * 64 + col];
    const int mvB = mb[koff0 + t * 64 + 32 + col];
    if (t < 15) {
      stage(cur ^ 1, t + 1);
      // outstanding: 4 (tile t) + 2 (mask) + 4 (tile t+1) = 10 -> wait to 6
      asm volatile("s_waitcnt vmcnt(6)" ::: "memory");
    } else {
      asm volatile("s_waitcnt vmcnt(0)" ::: "memory");
    }
    __builtin_amdgcn_s_barrier();  // all waves' chunks of tile t visible

#pragma unroll
    for (int sub = 0; sub < 2; ++sub) {
      const int mv = (sub == 0) ? mvA : mvB;
      // K A-frags from LDS (swizzled groups)
      const bf16* Krow = &Kl[s][cur][(sub * 32 + col) * 64];
      bf16x8 ak0 = *(const bf16x8*)(Krow + (((0 + hi) ^ c7) << 3));
      bf16x8 ak1 = *(const bf16x8*)(Krow + (((2 + hi) ^ c7) << 3));
      bf16x8 ak2 = *(const bf16x8*)(Krow + (((4 + hi) ^ c7) << 3));
      bf16x8 ak3 = *(const bf16x8*)(Krow + (((6 + hi) ^ c7) << 3));
      // S^T = K @ Q^T
      f32x16 st;
#pragma unroll
      for (int r = 0; r < 16; ++r) st[r] = 0.f;
      __builtin_amdgcn_s_setprio(1);
      st = MFMA32(ak0, bq[0], st);
      st = MFMA32(ak1, bq[1], st);
      st = MFMA32(ak2, bq[2], st);
      st = MFMA32(ak3, bq[3], st);
      __builtin_amdgcn_s_setprio(0);
      // mask (wave-uniform skip when all-ones)
      unsigned km32 = (unsigned)__ballot(mv != 0);
      if (km32 != 0xffffffffu) {
        unsigned km = km32 >> (hi * 4);
#pragma unroll
        for (int r = 0; r < 16; ++r)
          if (!((km >> ((r & 3) + 8 * (r >> 2))) & 1)) st[r] = -1e30f;
      }
      // per-half row max
      float m01 = fmaxf(st[0], st[1]), m23 = fmaxf(st[2], st[3]);
      float m45 = fmaxf(st[4], st[5]), m67 = fmaxf(st[6], st[7]);
      float m89 = fmaxf(st[8], st[9]), mab = fmaxf(st[10], st[11]);
      float mcd = fmaxf(st[12], st[13]), mef = fmaxf(st[14], st[15]);
      float m0 = fmaxf(fmaxf(fmaxf(m01, m23), fmaxf(m45, m67)),
                       fmaxf(fmaxf(m89, mab), fmaxf(mcd, mef)));
      // defer-max rescale (rare)
      if (__any(m0 > mrun + 8.0f)) {
        float pm = fmaxf(m0, __shfl_xor(m0, 32));
        float mnew = fmaxf(mrun, pm);
        float scale = fexp2(mrun - mnew);
        mrun = mnew;
        lrun *= scale;
        if (hi == 0) sws[w][col] = scale;
        asm volatile("s_waitcnt lgkmcnt(0)" ::: "memory");
#pragma unroll
        for (int r = 0; r < 16; ++r) {
          float sc = sws[w][(r & 3) + 8 * (r >> 2) + 4 * hi];
          o0[r] *= sc; o1[r] *= sc;
        }
      }
      // P = exp2(S - m) in place (raw v_exp_f32); per-half row-sum into lrun
#pragma unroll
      for (int r = 0; r < 16; ++r) st[r] = fexp2(st[r] - mrun);
      float s01 = st[0] + st[1], s23 = st[2] + st[3], s45 = st[4] + st[5];
      float s67 = st[6] + st[7], s89 = st[8] + st[9], sab = st[10] + st[11];
      float scd = st[12] + st[13], sef = st[14] + st[15];
      lrun += ((s01 + s23) + (s45 + s67)) + ((s89 + sab) + (scd + sef));
      // P -> bf16 A-frags: 8 cvt_pk + 4 cross-half exchanges in one window
      unsigned d0 = cvt_pk_bf16(st[0], st[1]);
      unsigned d1 = cvt_pk_bf16(st[2], st[3]);
      unsigned d2 = cvt_pk_bf16(st[4], st[5]);
      unsigned d3 = cvt_pk_bf16(st[6], st[7]);
      unsigned d4 = cvt_pk_bf16(st[8], st[9]);
      unsigned d5 = cvt_pk_bf16(st[10], st[11]);
      unsigned d6 = cvt_pk_bf16(st[12], st[13]);
      unsigned d7 = cvt_pk_bf16(st[14], st[15]);
      unsigned g02 = (unsigned)__shfl_xor((int)(hi ? d0 : d2), 32);
      unsigned g13 = (unsigned)__shfl_xor((int)(hi ? d1 : d3), 32);
      unsigned g46 = (unsigned)__shfl_xor((int)(hi ? d4 : d6), 32);
      unsigned g57 = (unsigned)__shfl_xor((int)(hi ? d5 : d7), 32);
      u32x4 w0 = {hi ? g02 : d0, hi ? g13 : d1, hi ? d2 : g02, hi ? d3 : g13};
      u32x4 w1 = {hi ? g46 : d4, hi ? g57 : d5, hi ? d6 : g46, hi ? d7 : g57};
      bf16x8 pa0 = __builtin_bit_cast(bf16x8, w0);
      bf16x8 pa1 = __builtin_bit_cast(bf16x8, w1);
      // V B-frags from LDS
      const bf16* Vrow0 = &Vl[s][cur][col * 64];
      const bf16* Vrow1 = &Vl[s][cur][(col + 32) * 64];
      const int g0 = ((sub * 4 + hi) ^ c7) << 3;
      const int g1 = ((sub * 4 + 2 + hi) ^ c7) << 3;
      bf16x8 bv00 = *(const bf16x8*)(Vrow0 + g0);
      bf16x8 bv10 = *(const bf16x8*)(Vrow0 + g1);
      bf16x8 bv01 = *(const bf16x8*)(Vrow1 + g0);
      bf16x8 bv11 = *(const bf16x8*)(Vrow1 + g1);
      // O += P @ V
      __builtin_amdgcn_s_setprio(1);
      o0 = MFMA32(pa0, bv00, o0);
      o0 = MFMA32(pa1, bv10, o0);
      o1 = MFMA32(pa0, bv01, o1);
      o1 = MFMA32(pa1, bv11, o1);
      __builtin_amdgcn_s_setprio(0);
    }
  }

  // ---- in-LDS merge of the 2 KV-split partials ----
  lrun += __shfl_xor(lrun, 32);  // fold per-half l partials
  if (hi == 0) { mlL[s][wq][0][col] = mrun; mlL[s][wq][1][col] = lrun; }
  __syncthreads();  // all loop LDS reads done; mlL visible

  float* Ol = (float*)Kl;  // 32 KB staging region, dead now: [wq][r][half][lane]
  if (s == 1) {
#pragma unroll
    for (int r = 0; r < 16; ++r) {
      Ol[(wq * 16 + r) * 128 + lane] = o0[r];
      Ol[(wq * 16 + r) * 128 + 64 + lane] = o1[r];
    }
  }
  __syncthreads();  // split-1 O visible

  if (s == 0) {
#pragma unroll
    for (int r = 0; r < 16; ++r) {
      const int qr = (r & 3) + 8 * (r >> 2) + 4 * hi;
      float m0v = mlL[0][wq][0][qr], l0v = mlL[0][wq][1][qr];
      float m1v = mlL[1][wq][0][qr], l1v = mlL[1][wq][1][qr];
      float ms = fmaxf(m0v, m1v);
      float w0v = fexp2(m0v - ms), w1v = fexp2(m1v - ms);
      float inv = 1.0f / (w0v * l0v + w1v * l1v);
      float v0 = (w0v * o0[r] + w1v * Ol[(wq * 16 + r) * 128 + lane]) * inv;
      float v1 = (w0v * o1[r] + w1v * Ol[(wq * 16 + r) * 128 + 64 + lane]) * inv;
      long base = ((long)b * 2048 + q0 + qr) * 1024 + h * 64 + col;
      Aout[base] = (bf16)v0;
      Aout[base + 32] = (bf16)v1;
    }
  }
}

// ---------------- launcher ----------------
extern "C" void kernel_launch(void* const* d_in, const int* in_sizes, int n_in,
                              void* d_out, int out_size, void* d_ws,
                              size_t ws_size, hipStream_t stream) {
  const float* x    = (const float*)d_in[0];
  const int*   mask = (const int*)d_in[1];
  const float* Wqkv = (const float*)d_in[2];
  const float* bqkv = (const float*)d_in[3];
  const float* Wout = (const float*)d_in[4];
  const float* bout = (const float*)d_in[5];
  float* out = (float*)d_out;

  char* ws = (char*)d_ws;
  bf16* xb    = (bf16*)(ws);                      // 8 MB; reused as Aatt
  bf16* wqkvT = (bf16*)(ws + (8u << 20));         // 6 MB
  bf16* woutT = (bf16*)(ws + (14u << 20));        // 2 MB
  bf16* Qb    = (bf16*)(ws + (16u << 20));        // 8 MB (b,h,t,d)
  bf16* Kb    = (bf16*)(ws + (24u << 20));        // 8 MB (b,h,t,d)
  bf16* VTb   = (bf16*)(ws + (32u << 20));        // 8 MB (b,h,d,t)
  bf16* Aatt  = xb;

  cast_bf16_kernel<<<4096, 256, 0, stream>>>(x, xb, (4096 * 1024) / 4);
  transpose_cast_kernel<<<dim3(48, 16), 256, 0, stream>>>(Wqkv, wqkvT, 1024, 3072);
  transpose_cast_kernel<<<dim3(16, 16), 256, 0, stream>>>(Wout, woutT, 1024, 1024);
  gemm_bt<0><<<dim3(32, 24), 256, 0, stream>>>(xb, wqkvT, bqkv, Qb, Kb, VTb,
                                               nullptr, 1024);
  attn_kernel<<<512, 512, 0, stream>>>(Qb, Kb, VTb, mask, Aatt);
  gemm_bt<1><<<dim3(32, 8), 256, 0, stream>>>(Aatt, woutT, bout, nullptr,
                                              nullptr, nullptr, out, 1024);
}